// Round 1
// baseline (446.714 us; speedup 1.0000x reference)
//
#include <hip/hip_runtime.h>

#define KSPLIT 4

// ---------------- device helpers ----------------

__device__ __forceinline__ float red32(float v){
  #pragma unroll
  for(int m=16;m;m>>=1) v += __shfl_xor(v, m, 32);
  return v;
}

// t = logmap0(expmap0(x)) for one row distributed over 32 lanes (lane j holds x_j)
__device__ __forceinline__ float logexp_rt(float x){
  const float sc = 1.4142135623730951f; // sqrt(2)
  float n  = sqrtf(red32(x*x));
  float n1 = fmaxf(n, 1e-6f);
  float a  = sc*n1;
  float p  = tanhf(a)/a * x;
  float np = sqrtf(red32(p*p));
  float np1= fmaxf(np, 1e-6f);
  float s  = fminf(sc*np1, 1.0f - 1e-5f);
  float at = 0.5f*logf((1.f+s)/(1.f-s));   // arctanh(s)
  return at/(sc*np1) * p;
}

// out_j = b[j] + sum_k tv_k * W[k][j]  (W row-major [32][32], tv distributed over lanes)
__device__ __forceinline__ float matvec32(float tv, const float* __restrict__ W,
                                          const float* __restrict__ bb, int j){
  float acc = bb[j];
  #pragma unroll
  for(int k=0;k<32;k++) acc = fmaf(__shfl(tv, k, 32), W[k*32+j], acc);
  return acc;
}

__device__ __forceinline__ float psum4(const float* __restrict__ P, int N, int idx){
  int s = N*32;
  return P[idx] + P[s+idx] + P[2*s+idx] + P[3*s+idx];
}

// ---------------- graph-chain kernels ----------------

// K1: u_g = logexp(gather(emb_g))@We_g + be_g for g in {SH,SS,HH}; store x1_sh
__global__ __launch_bounds__(256) void k_prep(
    const int* __restrict__ xsh, const int* __restrict__ xss, const int* __restrict__ xhh,
    const float* __restrict__ embSH, const float* __restrict__ embSS, const float* __restrict__ embHH,
    const float* __restrict__ We_sh, const float* __restrict__ be_sh,
    const float* __restrict__ We_ss, const float* __restrict__ be_ss,
    const float* __restrict__ We_hh, const float* __restrict__ be_hh,
    float* __restrict__ x1sh, float* __restrict__ ush,
    float* __restrict__ uss, float* __restrict__ uhh)
{
  int t = threadIdx.x, j = t&31;
  int g = blockIdx.x*8 + (t>>5);
  if(g >= 2390) return;
  const int* xi; const float* emb; const float* We; const float* be; float* uo; int r;
  float* x1o = nullptr;
  if(g < 1195){ r=g;      xi=xsh; emb=embSH; We=We_sh; be=be_sh; uo=ush; x1o=x1sh; }
  else if(g < 1585){ r=g-1195; xi=xss; emb=embSS; We=We_ss; be=be_ss; uo=uss; }
  else {            r=g-1585; xi=xhh; emb=embHH; We=We_hh; be=be_hh; uo=uhh; }
  float x = emb[xi[r]*32 + j];
  if(x1o) x1o[r*32+j] = x;
  float tv = logexp_rt(x);
  uo[r*32+j] = matvec32(tv, We, be, j);
}

struct AdjCfg { const float* S; const float* X; float* P; int N; int nrb; };

// adj partial matmul: P[ks][r][j] += S[r, krange_ks] @ X[krange_ks, j]
// 16 rows/block, half-wave per row (lane j holds column j), KSPLIT k-ranges.
__global__ __launch_bounds__(256) void k_adj(AdjCfg c0, AdjCfg c1, AdjCfg c2, int e0, int e1)
{
  __shared__ float Xl[64][33];
  int b = blockIdx.x;
  AdjCfg c; int local;
  if(b < e0){ c = c0; local = b; }
  else if(b < e1){ c = c1; local = b - e0; }
  else { c = c2; local = b - e1; }
  int ks = local / c.nrb, rb = local % c.nrb;
  int N = c.N;
  int klen = (N + KSPLIT - 1)/KSPLIT;
  int kbeg = ks*klen, kend = min(kbeg+klen, N);
  int t = threadIdx.x, j = t&31, hw = t>>5;
  int r0 = rb*16;
  int ra = r0 + hw, rbv = r0 + hw + 8;
  bool va = ra < N, vb = rbv < N;
  const float* __restrict__ Sa = c.S + (long)(va? ra : 0) * N;
  const float* __restrict__ Sb = c.S + (long)(vb? rbv: 0) * N;
  float acc0 = 0.f, acc1 = 0.f;
  for(int k0 = kbeg; k0 < kend; k0 += 64){
    int kc = min(64, kend - k0);
    __syncthreads();
    #pragma unroll
    for(int q=0;q<8;q++){
      int e = t + 256*q; int kr = e>>5, jj = e&31;
      Xl[kr][jj] = (kr < kc) ? c.X[(k0+kr)*32 + jj] : 0.f;
    }
    __syncthreads();
    if(kc == 64){
      #pragma unroll 16
      for(int k=0;k<64;k++){
        float x = Xl[k][j];
        acc0 = fmaf(Sa[k0+k], x, acc0);
        acc1 = fmaf(Sb[k0+k], x, acc1);
      }
    } else {
      for(int k=0;k<kc;k++){
        float x = Xl[k][j];
        acc0 = fmaf(Sa[k0+k], x, acc0);
        acc1 = fmaf(Sb[k0+k], x, acc1);
      }
    }
  }
  float* P = c.P + (long)ks * N * 32;
  if(va) P[ra *32 + j] = acc0;
  if(vb) P[rbv*32 + j] = acc1;
}

// P1: w_g = logexp(relu(sum_parts v_g)) @ Wd_g + bd_g    (all 3 graphs)
__global__ __launch_bounds__(256) void k_pw1(
    const float* __restrict__ pvsh, const float* __restrict__ pvss, const float* __restrict__ pvhh,
    const float* __restrict__ Wd_sh, const float* __restrict__ bd_sh,
    const float* __restrict__ Wd_ss, const float* __restrict__ bd_ss,
    const float* __restrict__ Wd_hh, const float* __restrict__ bd_hh,
    float* __restrict__ wsh, float* __restrict__ wss, float* __restrict__ whh)
{
  int t=threadIdx.x, j=t&31;
  int g = blockIdx.x*8 + (t>>5);
  if(g>=2390) return;
  const float* P; const float* Wd; const float* bd; float* w; int r, N;
  if(g<1195){ r=g;      N=1195; P=pvsh; Wd=Wd_sh; bd=bd_sh; w=wsh; }
  else if(g<1585){ r=g-1195; N=390; P=pvss; Wd=Wd_ss; bd=bd_ss; w=wss; }
  else {          r=g-1585; N=805; P=pvhh; Wd=Wd_hh; bd=bd_hh; w=whh; }
  float v = psum4(P, N, r*32+j);
  float tv = logexp_rt(fmaxf(v, 0.f));
  w[r*32+j] = matvec32(tv, Wd, bd, j);
}

// P2: SH: x2=sum, u2=logexp(x2)@We2+be2 ; SS: xss2=sum ; HH: xhh2=[sum,kg]@W_L+b_L
__global__ __launch_bounds__(256) void k_pw2(
    const float* __restrict__ pxsh, const float* __restrict__ pxss, const float* __restrict__ pxhh,
    const float* __restrict__ We2, const float* __restrict__ be2,
    const float* __restrict__ kg, const float* __restrict__ W_L, const float* __restrict__ b_L,
    float* __restrict__ x2, float* __restrict__ u2,
    float* __restrict__ xss2, float* __restrict__ xhh2)
{
  int t=threadIdx.x, j=t&31;
  int g = blockIdx.x*8 + (t>>5);
  if(g>=2390) return;
  if(g < 1195){
    int r = g;
    float v = psum4(pxsh, 1195, r*32+j);
    x2[r*32+j] = v;
    u2[r*32+j] = matvec32(logexp_rt(v), We2, be2, j);
  } else if(g < 1585){
    int r = g-1195;
    xss2[r*32+j] = psum4(pxss, 390, r*32+j);
  } else {
    int r = g-1585;
    float v = psum4(pxhh, 805, r*32+j);
    float acc = b_L[j];
    #pragma unroll
    for(int k=0;k<32;k++) acc = fmaf(__shfl(v,k,32), W_L[k*32+j], acc);
    #pragma unroll
    for(int k=0;k<27;k++) acc = fmaf(kg[r*27+k], W_L[(32+k)*32+j], acc);
    xhh2[r*32+j] = acc;
  }
}

// P3 (generic single-graph decode pointwise)
__global__ __launch_bounds__(256) void k_pwdec1(
    const float* __restrict__ P, int N,
    const float* __restrict__ Wd, const float* __restrict__ bd, float* __restrict__ w)
{
  int t=threadIdx.x, j=t&31;
  int r = blockIdx.x*8 + (t>>5);
  if(r>=N) return;
  float v = psum4(P, N, r*32+j);
  w[r*32+j] = matvec32(logexp_rt(fmaxf(v,0.f)), Wd, bd, j);
}

// P4: y = ((x2 + x5 + x1@Wsh+bsh)/3) @ Wmlp1 + bmlp1
__global__ __launch_bounds__(256) void k_pw4(
    const float* __restrict__ px5, const float* __restrict__ x2, const float* __restrict__ x1,
    const float* __restrict__ Wsh, const float* __restrict__ bsh,
    const float* __restrict__ W1, const float* __restrict__ b1, float* __restrict__ y)
{
  int t=threadIdx.x, j=t&31;
  int r = blockIdx.x*8 + (t>>5);
  if(r>=1195) return;
  int idx = r*32+j;
  float x5 = psum4(px5, 1195, idx);
  float a  = matvec32(x1[idx], Wsh, bsh, j);
  float xv = (x2[idx] + x5 + a) / 3.0f;
  y[idx] = matvec32(xv, W1, b1, j);
}

// K6: batch-norm stats over y [1195,32] (two-pass), emit scale/shift
__global__ __launch_bounds__(1024) void k_bn1(
    const float* __restrict__ y, const float* __restrict__ g, const float* __restrict__ b,
    float* __restrict__ scl, float* __restrict__ sft)
{
  __shared__ float r1[32][33];
  __shared__ float msh[32];
  int t=threadIdx.x; int j=t&31, rg=t>>5;
  float s1=0.f;
  for(int r=rg;r<1195;r+=32) s1 += y[r*32+j];
  r1[rg][j] = s1;
  __syncthreads();
  if(t<32){ float S=0.f; for(int q=0;q<32;q++) S += r1[q][t]; msh[t] = S/1195.f; }
  __syncthreads();
  float m = msh[j];
  float s2=0.f;
  for(int r=rg;r<1195;r+=32){ float d = y[r*32+j]-m; s2 += d*d; }
  __syncthreads();
  r1[rg][j] = s2;
  __syncthreads();
  if(t<32){
    float S=0.f; for(int q=0;q<32;q++) S += r1[q][t];
    float var = S/1195.f;
    float sc = g[t]*rsqrtf(var + 1e-5f);
    scl[t] = sc; sft[t] = b[t] - msh[t]*sc;
  }
}

// K7: es/eh = concat(tanh(bn(y)), x_ss2|x_hh2) @ W + b
__global__ __launch_bounds__(256) void k_eseh(
    const float* __restrict__ y, const float* __restrict__ scl1, const float* __restrict__ sft1,
    const float* __restrict__ xss2, const float* __restrict__ xhh2,
    const float* __restrict__ W_cs, const float* __restrict__ b_cs,
    const float* __restrict__ W_ch, const float* __restrict__ b_ch,
    float* __restrict__ es, float* __restrict__ eh)
{
  int t=threadIdx.x, j=t&31;
  int r = blockIdx.x*8 + (t>>5);
  if(r>=1195) return;
  float xr = tanhf(fmaf(y[r*32+j], scl1[j], sft1[j]));
  const float* W; const float* bb; const float* x2p; float* o;
  if(r < 390){ W=W_cs; bb=b_cs; x2p = xss2 + r*32;      o = es + r*32; }
  else       { W=W_ch; bb=b_ch; x2p = xhh2 + (r-390)*32; o = eh + (r-390)*32; }
  float c2 = x2p[j];
  float acc = bb[j];
  #pragma unroll
  for(int k=0;k<32;k++){
    acc = fmaf(__shfl(xr, k, 32), W[k*32+j],      acc);
    acc = fmaf(__shfl(c2, k, 32), W[(32+k)*32+j], acc);
  }
  o[j] = acc;
}

// ---------------- big kernels ----------------

// KB1: t = ((P @ es) / rowsum(P)) @ W_mlp + b_mlp, plus f64 atomic batch stats
__global__ __launch_bounds__(256) void k_pgemm(
    const float* __restrict__ P, const float* __restrict__ es,
    const float* __restrict__ Wm, const float* __restrict__ bm,
    float* __restrict__ tout, double* __restrict__ stats)
{
  __shared__ __align__(16) float Pl[64][68];
  __shared__ float esl[64][33];
  __shared__ float red[2][8][33];
  int t = threadIdx.x, j = t&31, isub = t>>5;
  long i0 = (long)blockIdx.x * 64;
  float acc[8], ps[8];
  #pragma unroll
  for(int a=0;a<8;a++){ acc[a]=0.f; ps[a]=0.f; }
  for(int k0=0;k0<390;k0+=64){
    __syncthreads();
    #pragma unroll
    for(int q=0;q<8;q++){               // P chunk: rows isub+8q, float2 cols
      int row = isub + 8*q, c2 = j;
      int kk = k0 + 2*c2;
      float2 v = make_float2(0.f,0.f);
      if(kk < 390) v = *(const float2*)(P + (i0+row)*390 + kk);  // 390 even, kk even -> 8B aligned, pairs never split
      Pl[row][2*c2]   = v.x;
      Pl[row][2*c2+1] = v.y;
      ps[q] += v.x + v.y;               // free row-sum: rows match compute rows
    }
    #pragma unroll
    for(int q=0;q<8;q++){               // es chunk
      int kr = isub + 8*q, jj = j;
      esl[kr][jj] = (k0+kr < 390) ? es[(k0+kr)*32 + jj] : 0.f;
    }
    __syncthreads();
    #pragma unroll
    for(int k4=0;k4<16;k4++){
      float4 pv[8];
      #pragma unroll
      for(int a=0;a<8;a++) pv[a] = *(const float4*)&Pl[isub+8*a][4*k4];
      #pragma unroll
      for(int kk=0;kk<4;kk++){
        float ev = esl[4*k4+kk][j];
        #pragma unroll
        for(int a=0;a<8;a++) acc[a] = fmaf(((const float*)&pv[a])[kk], ev, acc[a]);
      }
    }
  }
  float en[8];
  #pragma unroll
  for(int a=0;a<8;a++){
    float rs = red32(ps[a]);
    en[a] = acc[a] / rs;
  }
  float tm[8]; float bmj = bm[j];
  #pragma unroll
  for(int a=0;a<8;a++) tm[a] = bmj;
  for(int k=0;k<32;k++){
    float wv = Wm[k*32+j];
    #pragma unroll
    for(int a=0;a<8;a++) tm[a] = fmaf(__shfl(en[a], k, 32), wv, tm[a]);
  }
  float s1=0.f, s2=0.f;
  #pragma unroll
  for(int a=0;a<8;a++){
    tout[(i0 + isub + 8*a)*32 + j] = tm[a];
    s1 += tm[a]; s2 += tm[a]*tm[a];
  }
  red[0][isub][j] = s1; red[1][isub][j] = s2;
  __syncthreads();
  if(t < 32){
    float S1=0.f, S2=0.f;
    #pragma unroll
    for(int g2=0; g2<8; g2++){ S1 += red[0][g2][t]; S2 += red[1][g2][t]; }
    atomicAdd(&stats[t],    (double)S1);
    atomicAdd(&stats[32+t], (double)S2);
  }
}

// KB2: finalize big BN scale/shift
__global__ __launch_bounds__(64) void k_bnfin(
    const double* __restrict__ stats, const float* __restrict__ g, const float* __restrict__ b,
    float* __restrict__ scl, float* __restrict__ sft)
{
  int j = threadIdx.x; if(j>=32) return;
  double mean = stats[j] * (1.0/32768.0);
  double var  = stats[32+j] * (1.0/32768.0) - mean*mean;
  float sc = g[j] * rsqrtf((float)var + 1e-5f);
  scl[j] = sc; sft[j] = b[j] - (float)mean*sc;
}

// KB3: out = relu(t*scale+shift) @ eh^T   (128 rows x 64 cols per block)
__global__ __launch_bounds__(256) void k_out(
    const float* __restrict__ tin, const float* __restrict__ eh,
    const float* __restrict__ scl, const float* __restrict__ sft,
    float* __restrict__ out)
{
  __shared__ __align__(16) float zt[4][32][36];  // [wave][k][ri] ; row i = 4*ri + w
  __shared__ float el[32][68];                   // [k][j]
  int t = threadIdx.x;
  int w = t>>6, lane = t&63;
  long i0 = (long)(blockIdx.x & 255) * 128;
  int  j0 = (int)(blockIdx.x >> 8) * 64;
  int kf = t&31, ib = t>>5;
  float sc = scl[kf], sh = sft[kf];
  #pragma unroll
  for(int q=0;q<16;q++){                 // stage z (bn+relu applied)
    int i = ib + 8*q;
    float v = tin[(i0+i)*32 + kf];
    v = fmaxf(fmaf(v, sc, sh), 0.f);
    zt[i&3][kf][i>>2] = v;
  }
  #pragma unroll
  for(int q=0;q<8;q++){                  // stage eh transposed
    int jr = ib + 8*q;
    int jg = j0 + jr;
    el[kf][jr] = (jg < 805) ? eh[(long)jg*32 + kf] : 0.f;
  }
  __syncthreads();
  float acc[32];
  #pragma unroll
  for(int a=0;a<32;a++) acc[a]=0.f;
  #pragma unroll 4
  for(int k=0;k<32;k++){
    float ev = el[k][lane];
    #pragma unroll
    for(int q4=0;q4<8;q4++){
      float4 zv = *(const float4*)&zt[w][k][4*q4];
      acc[4*q4+0] = fmaf(zv.x, ev, acc[4*q4+0]);
      acc[4*q4+1] = fmaf(zv.y, ev, acc[4*q4+1]);
      acc[4*q4+2] = fmaf(zv.z, ev, acc[4*q4+2]);
      acc[4*q4+3] = fmaf(zv.w, ev, acc[4*q4+3]);
    }
  }
  int jg = j0 + lane;
  if(jg < 805){
    #pragma unroll
    for(int ri=0;ri<32;ri++){
      long row = i0 + 4*ri + w;
      out[row*805 + jg] = acc[ri];     // 64 consecutive floats per wave-store: coalesced
    }
  }
}

// ---------------- launcher ----------------

extern "C" void kernel_launch(void* const* d_in, const int* in_sizes, int n_in,
                              void* d_out, int out_size, void* d_ws, size_t ws_size,
                              hipStream_t stream)
{
  const int*   x_SH  = (const int*)  d_in[0];
  const float* S_SH  = (const float*)d_in[1];
  const int*   x_SS  = (const int*)  d_in[2];
  const float* S_SS  = (const float*)d_in[3];
  const int*   x_HH  = (const int*)  d_in[4];
  const float* S_HH  = (const float*)d_in[5];
  const float* presc = (const float*)d_in[6];
  const float* kg    = (const float*)d_in[7];
  const float* embSH = (const float*)d_in[8];
  const float* embSS = (const float*)d_in[9];
  const float* embHH = (const float*)d_in[10];
  const float* We_sh = (const float*)d_in[11]; const float* be_sh = (const float*)d_in[12];
  const float* Wd_sh = (const float*)d_in[13]; const float* bd_sh = (const float*)d_in[14];
  const float* We_sh2= (const float*)d_in[15]; const float* be_sh2= (const float*)d_in[16];
  const float* Wd_sh2= (const float*)d_in[17]; const float* bd_sh2= (const float*)d_in[18];
  const float* We_ss = (const float*)d_in[19]; const float* be_ss = (const float*)d_in[20];
  const float* Wd_ss = (const float*)d_in[21]; const float* bd_ss = (const float*)d_in[22];
  const float* We_hh = (const float*)d_in[23]; const float* be_hh = (const float*)d_in[24];
  const float* Wd_hh = (const float*)d_in[25]; const float* bd_hh = (const float*)d_in[26];
  const float* W_shems=(const float*)d_in[27]; const float* b_shems=(const float*)d_in[28];
  const float* W_mlp1= (const float*)d_in[29]; const float* b_mlp1= (const float*)d_in[30];
  const float* g_bn1 = (const float*)d_in[31]; const float* bb_bn1= (const float*)d_in[32];
  const float* W_cs  = (const float*)d_in[33]; const float* b_cs  = (const float*)d_in[34];
  const float* W_ch  = (const float*)d_in[35]; const float* b_ch  = (const float*)d_in[36];
  const float* W_L   = (const float*)d_in[37]; const float* b_L   = (const float*)d_in[38];
  const float* W_mlp = (const float*)d_in[39]; const float* b_mlp = (const float*)d_in[40];
  const float* g_si  = (const float*)d_in[41]; const float* bb_si = (const float*)d_in[42];
  float* outp = (float*)d_out;

  float* wsf = (float*)d_ws;
  size_t off = 0;
  auto alloc = [&](size_t n){ float* p = wsf + off; off += (n + 3) & ~(size_t)3; return p; };
  float* t_buf = alloc(32768UL*32);
  float* psh   = alloc(4UL*1195*32);
  float* pss   = alloc(4UL*390*32);
  float* phh   = alloc(4UL*805*32);
  float* x1    = alloc(1195*32);
  float* ush   = alloc(1195*32);
  float* wsh   = alloc(1195*32);
  float* x2    = alloc(1195*32);
  float* u2    = alloc(1195*32);
  float* w2    = alloc(1195*32);
  float* ybuf  = alloc(1195*32);
  float* uss   = alloc(390*32);
  float* wss_  = alloc(390*32);
  float* xss2  = alloc(390*32);
  float* uhh   = alloc(805*32);
  float* whh_  = alloc(805*32);
  float* xhh2  = alloc(805*32);
  float* esb   = alloc(390*32);
  float* ehb   = alloc(805*32);
  float* scl1  = alloc(32); float* sft1 = alloc(32);
  float* scl2  = alloc(32); float* sft2 = alloc(32);
  double* stats = (double*)(wsf + off); off += 128; // 64 doubles

  // --- graph chain ---
  k_prep<<<299,256,0,stream>>>(x_SH,x_SS,x_HH, embSH,embSS,embHH,
                               We_sh,be_sh, We_ss,be_ss, We_hh,be_hh,
                               x1, ush, uss, uhh);

  AdjCfg a0{S_SH, ush, psh, 1195, 75}, a1{S_SS, uss, pss, 390, 25}, a2{S_HH, uhh, phh, 805, 51};
  k_adj<<<604,256,0,stream>>>(a0,a1,a2, 300, 400);

  k_pw1<<<299,256,0,stream>>>(psh,pss,phh, Wd_sh,bd_sh, Wd_ss,bd_ss, Wd_hh,bd_hh,
                              wsh, wss_, whh_);

  AdjCfg b0{S_SH, wsh, psh, 1195, 75}, b1{S_SS, wss_, pss, 390, 25}, b2{S_HH, whh_, phh, 805, 51};
  k_adj<<<604,256,0,stream>>>(b0,b1,b2, 300, 400);

  k_pw2<<<299,256,0,stream>>>(psh,pss,phh, We_sh2,be_sh2, kg, W_L,b_L,
                              x2, u2, xss2, xhh2);

  AdjCfg c0{S_SH, u2, psh, 1195, 75};
  k_adj<<<300,256,0,stream>>>(c0,c0,c0, 300, 300);

  k_pwdec1<<<150,256,0,stream>>>(psh, 1195, Wd_sh2, bd_sh2, w2);

  AdjCfg d0{S_SH, w2, psh, 1195, 75};
  k_adj<<<300,256,0,stream>>>(d0,d0,d0, 300, 300);

  k_pw4<<<150,256,0,stream>>>(psh, x2, x1, W_shems,b_shems, W_mlp1,b_mlp1, ybuf);

  k_bn1<<<1,1024,0,stream>>>(ybuf, g_bn1, bb_bn1, scl1, sft1);

  k_eseh<<<150,256,0,stream>>>(ybuf, scl1, sft1, xss2, xhh2,
                               W_cs,b_cs, W_ch,b_ch, esb, ehb);

  // --- big part ---
  hipMemsetAsync(stats, 0, 64*sizeof(double), stream);
  k_pgemm<<<512,256,0,stream>>>(presc, esb, W_mlp, b_mlp, t_buf, stats);
  k_bnfin<<<1,64,0,stream>>>(stats, g_si, bb_si, scl2, sft2);
  k_out<<<256*13,256,0,stream>>>(t_buf, ehb, scl2, sft2, outp);
}